// Round 10
// baseline (91.291 us; speedup 1.0000x reference)
//
#include <hip/hip_runtime.h>
#include <hip/hip_fp16.h>

#define B 128
#define L 1024
// triangular decomposition: 16 col-segments of 64; 2 row-bands of 512.
// tiles: band0 q=0..15 (tl=q), band1 q=8..15 (tl=q+8). 24 tiles/batch.
// Balanced block mapping (R16): block k<8: tiles {k, 23-k} (9 row-iters);
// block k>=8: tile {k} (8 iters). 16 blocks/batch, row staged once.
#define NTILE 24
#define TSTRIDE 576   // per-tile ws slice: 512 row partials + 64 col partials

#if __has_builtin(__builtin_amdgcn_exp2f)
#define EXP2(x) __builtin_amdgcn_exp2f(x)
#else
#define EXP2(x) __expf((x) * 0.6931471805599453f)
#endif

typedef unsigned int uint4v __attribute__((ext_vector_type(4)));

// ws layout (floats):
//   [0 .. B*24*576)    per-(b,tile) slices: rows[512] then cols[64]
//   tail accumulators (all zeroed by pair block 0; consumed by gf_kernel
//   across the dispatch boundary):
//   [WS_DCG  + b]      per-batch dcg accumulator (float atomic)
//   [WS_QCTR + b]      per-batch quarter counter (int atomic)
//   [WS_CNT  + 2b]     per-batch packed grade counts (u64 atomic)
//   [WS_ACC]           ndcg accumulator
//   [WS_GCTR]          batch completion counter
#define WS_TAIL (B * NTILE * TSTRIDE)
#define WS_DCG  (WS_TAIL)
#define WS_QCTR (WS_TAIL + 128)
#define WS_CNT  (WS_TAIL + 256)
#define WS_ACC  (WS_TAIL + 512)
#define WS_GCTR (WS_TAIL + 513)
#define WS_ZWORDS 514

// erfc(|y|) ~= exp(-(1.12838 y + 0.6446 y^2 + 0.0745 y^3)), |dPhi| <= ~2.5e-4,
// y = diff/2 (prescaled into the f16 row). Constants pre-multiplied by
// -log2(e) so v_exp_f16 computes exp2 directly.
#define K1f -1.6279072f
#define K2f -0.9299637f
#define K3f -0.1074808f

// one packed evaluation: du holds 2 f16 j-values; returns erf(y_i - y_j) x2
// (signed, via v_bfi sign transfer). d==0 gives exactly 0 (e=1, r=0, +0 sign),
// so diagonal elements self-cancel. Math verified absmax=0.0 (R15/R16 runs).
__device__ __forceinline__ __half2 term2v(unsigned int du, __half2 pi2,
                                          __half2 k1, __half2 k2, __half2 k3,
                                          __half2 one2) {
    __half2 pj = __builtin_bit_cast(__half2, du);
    __half2 d  = __hsub2(pi2, pj);
    unsigned int dbits = __builtin_bit_cast(unsigned int, d);
    __half2 a  = __builtin_bit_cast(__half2, dbits & 0x7fff7fffu); // |d|
    __half2 t  = __hfma2(k3, a, k2);
    __half2 u  = __hfma2(t,  a, k1);
    __half2 w  = __hmul2(a, u);                      // <= 0
    __half2 e  = __halves2half2(hexp2(__low2half(w)),
                                hexp2(__high2half(w)));   // ~= erfc(|y|)
    __half2 r  = __hsub2(one2, e);                   // >= 0, sign bits clear
    unsigned int rs = (dbits & 0x80008000u)
                    | (__builtin_bit_cast(unsigned int, r) & 0x7fff7fffu);
    return __builtin_bit_cast(__half2, rs);          // erf(y), signed
}

// Antisymmetric (triangular) pair kernel, balanced mapping — byte-identical
// compute to the R16-verified version; only the tail zero-init changed.
// Sub-tiles (seg s in band r) x (seg q): s<q -> row+col accumulate;
// s==q -> full 64x64, ROW-ONLY (diag term = 0); s>q skipped (mirror covered
// by the (q,s) tile's col path). Erf work = 136/256 = 53% of full.
__global__ __launch_bounds__(256, 8) void pair_kernel(const float* __restrict__ preds,
                                                      const float* __restrict__ target,
                                                      float* __restrict__ ws) {
    __shared__ __align__(16) unsigned char smem[2048 + 8192 + 8192];
    __half* sph = (__half*)smem;
    float* rowLDS = (float*)(smem + 2048);
    unsigned int* colLDS = (unsigned int*)(smem + 2048 + 8192);
    float* col2LDS = (float*)(smem + 2048 + 8192);   // alias, low 2KB

    const int blk = blockIdx.x;
    const int b   = blk >> 4;
    const int kk  = blk & 15;
    const int tid = threadIdx.x;
    const int il  = tid & 63;
    const int jq  = tid >> 6;

    if (blk == 0) {
        // zero the tail accumulator region (visible to gf_kernel at the
        // dispatch boundary). float 0.0f == int 0 == all-zero bits.
        for (int k = tid; k < WS_ZWORDS; k += 256)
            ((unsigned int*)ws)[WS_TAIL + k] = 0u;
    }

    // stage full row as f16, prescaled by 0.5 (erf argument is diff/2)
    const float* prow = preds + b * L;
    float4 v4 = reinterpret_cast<const float4*>(prow)[tid];
    reinterpret_cast<__half2*>(sph)[tid * 2 + 0] = __floats2half2_rn(0.5f * v4.x, 0.5f * v4.y);
    reinterpret_cast<__half2*>(sph)[tid * 2 + 1] = __floats2half2_rn(0.5f * v4.z, 0.5f * v4.w);
    __syncthreads();

    const __half2 k1   = __floats2half2_rn(K1f, K1f);
    const __half2 k2   = __floats2half2_rn(K2f, K2f);
    const __half2 k3   = __floats2half2_rn(K3f, K3f);
    const __half2 one2 = __floats2half2_rn(1.0f, 1.0f);
    const __half2 z2   = __floats2half2_rn(0.0f, 0.0f);

    const int ntl = (kk < 8) ? 2 : 1;
    for (int tt = 0; tt < ntl; ++tt) {
        const int tl = tt ? (23 - kk) : kk;
        const int r  = (tl >= 16) ? 1 : 0;
        const int q  = r ? (tl - 8) : tl;

        const uint4v* cp4 = reinterpret_cast<const uint4v*>(sph + q * 64 + jq * 16);
        uint4v pq0 = cp4[0], pq1 = cp4[1];
        unsigned int pjb[8] = {pq0.x, pq0.y, pq0.z, pq0.w, pq1.x, pq1.y, pq1.z, pq1.w};

        __half2 colacc[8] = {z2, z2, z2, z2, z2, z2, z2, z2};

        const int r8 = r << 3;
        for (int rr = 0; rr < 8; ++rr) {   // rows: seg s = 8r+rr (uniform trip)
            const int s = r8 + rr;
            if (s > q) break;
            const bool ca = (s < q);       // col-accumulate? (uniform)
            const __half2 pi2 = __half2half2(sph[(s << 6) + il]);
            __half2 A = z2, Bc = z2;       // two 4-deep row chains
            #pragma unroll
            for (int m = 0; m < 8; ++m) {
                __half2 tm = term2v(pjb[m], pi2, k1, k2, k3, one2);
                if (m < 4) A = __hadd2(A, tm); else Bc = __hadd2(Bc, tm);
                if (ca) colacc[m] = __hadd2(colacc[m], tm);  // <=8 adds: f16 ok
            }
            float2 fA = __half22float2(A), fB = __half22float2(Bc);
            rowLDS[(rr << 8) + (jq << 6) + il] = (fA.x + fA.y) + (fB.x + fB.y);
        }

        #pragma unroll
        for (int m = 0; m < 8; ++m)
            colLDS[((jq << 3) + m) * 64 + il] = __builtin_bit_cast(unsigned int, colacc[m]);
        __syncthreads();

        float* wst = ws + (b * NTILE + tl) * TSTRIDE;

        // row writeout: 2 rows/thread, sum the 4 j-quarters. rr-slices beyond
        // this tile's trip carry stale data, never read by gf (q>=s filter).
        #pragma unroll
        for (int h = 0; h < 2; ++h) {
            int rho = tid + (h << 8);
            int rrx = rho >> 6, ilx = rho & 63;
            float v = (rowLDS[(rrx << 8) + ilx]       + rowLDS[(rrx << 8) + 64 + ilx])
                    + (rowLDS[(rrx << 8) + 128 + ilx] + rowLDS[(rrx << 8) + 192 + ilx]);
            wst[rho] = v;
        }

        // col reduce stage 1 (reads before barrier, aliased store after)
        float sx = 0.0f, sy = 0.0f;
        {
            int cp = tid & 31, ilq = tid >> 5;
            const uint4v* cl = reinterpret_cast<const uint4v*>(colLDS + cp * 64 + ilq * 8);
            uint4v c0 = cl[0], c1 = cl[1];
            unsigned int cc[8] = {c0.x, c0.y, c0.z, c0.w, c1.x, c1.y, c1.z, c1.w};
            #pragma unroll
            for (int m = 0; m < 8; ++m) {
                float2 f = __half22float2(__builtin_bit_cast(__half2, cc[m]));
                sx += f.x; sy += f.y;
            }
        }
        __syncthreads();
        {
            int cp = tid & 31, ilq = tid >> 5;
            col2LDS[ilq * 64 + cp * 2 + 0] = sx;
            col2LDS[ilq * 64 + cp * 2 + 1] = sy;
        }
        __syncthreads();

        if (tid < 64) {
            float cs = 0.0f;
            #pragma unroll
            for (int g = 0; g < 8; ++g) cs += col2LDS[g * 64 + tid];
            wst[512 + tid] = cs;
        }
        __syncthreads();                   // protect rowLDS/colLDS for next tile
    }
}

// Fused gather+finish. grid = B*4 = 512 blocks, 256 threads; one row/thread.
// Phase A (all blocks): gather Es (R16-verified indexing, unrolled with
// select-masks: poisoned ws values are discarded by cndmask BEFORE any fp op,
// so NaN/Inf poison cannot propagate), DCG contrib + grade-count, block
// reduce, per-batch atomic combine. Phase B (last quarter-block per batch):
// IDCG counting sort + ndcg; last batch writes the final scalar.
__global__ __launch_bounds__(256) void gf_kernel(const float* __restrict__ target,
                                                 float* __restrict__ ws,
                                                 float* __restrict__ out) {
    __shared__ unsigned long long cred[256];
    __shared__ float fred[256];
    __shared__ int lastflag;

    const int blk = blockIdx.x;
    const int b   = blk >> 2;
    const int tid = threadIdx.x;
    const int i   = ((blk & 3) << 8) + tid;
    const int u   = i >> 6;            // seg (wave-uniform)
    const int rb  = u >> 3;            // band
    const int rho = i & 511;
    const int i6  = i & 63;
    const int b24 = b * NTILE;

    // rowsum: 16 independent loads (pipelined), masked select per slot
    float rowsum = 0.0f;
    #pragma unroll
    for (int qq = 0; qq < 16; ++qq) {
        float v = ws[(b24 + qq + (rb << 3)) * TSTRIDE + rho];
        rowsum += (qq >= u) ? v : 0.0f;
    }
    float c1v = ws[(b24 + u) * TSTRIDE + 512 + i6];
    float c2v = ws[(b24 + u + 8) * TSTRIDE + 512 + i6];
    float cols = ((u >= 1) ? c1v : 0.0f) + ((u >= 9) ? c2v : 0.0f);

    float Es  = rowsum - cols;
    float er1 = 513.5f + 0.5f * Es;    // er+1 = 513.5 + Es/2 (diag term = 0)
    float tgt = target[b * L + i];
    float g   = EXP2(tgt) - 1.0f;      // 2^t - 1, exact for integer grades
    float contrib = g * __builtin_amdgcn_rcpf(__log2f(er1));

    unsigned long long cnt =
          ((unsigned long long)(tgt > 3.5f) << 48)
        + ((unsigned long long)(tgt > 2.5f) << 32)
        + ((unsigned long long)(tgt > 1.5f) << 16)
        + ((unsigned long long)(tgt > 0.5f));

    cred[tid] = cnt;
    fred[tid] = contrib;
    __syncthreads();
    #pragma unroll
    for (int s = 128; s > 0; s >>= 1) {
        if (tid < (unsigned)s) {
            cred[tid] += cred[tid + s];
            fred[tid] += fred[tid + s];
        }
        __syncthreads();
    }

    unsigned long long* cntA = (unsigned long long*)(ws + WS_CNT);
    if (tid == 0) {
        atomicAdd(&ws[WS_DCG + b], fred[0]);
        atomicAdd(&cntA[b], cred[0]);
        __threadfence();
        int pos = atomicAdd((int*)ws + WS_QCTR + b, 1);
        lastflag = (pos == 3);
    }
    __syncthreads();
    if (!lastflag) return;

    // ---- last quarter-block of batch b: IDCG + ndcg ----
    unsigned long long tot = atomicAdd(&cntA[b], 0ull);   // coherent read
    const int n4 = (int)(tot >> 48) & 0xFFFF;
    const int n3 = (int)(tot >> 32) & 0xFFFF;
    const int n2 = (int)(tot >> 16) & 0xFFFF;
    const int n1 = (int)(tot)       & 0xFFFF;

    float idcg_p = 0.0f;
    #pragma unroll
    for (int k = 0; k < 4; ++k) {
        int pos = tid + 1 + k * 256;
        float gain = (pos <= n4) ? 15.0f : (pos <= n3) ? 7.0f :
                     (pos <= n2) ? 3.0f  : (pos <= n1) ? 1.0f : 0.0f;
        idcg_p += gain * __builtin_amdgcn_rcpf(__log2f((float)pos + 1.0f));
    }
    fred[tid] = idcg_p;
    __syncthreads();
    #pragma unroll
    for (int s = 128; s > 0; s >>= 1) {
        if (tid < (unsigned)s) fred[tid] += fred[tid + s];
        __syncthreads();
    }

    if (tid == 0) {
        float dcg  = atomicAdd(&ws[WS_DCG + b], 0.0f);    // coherent read
        float ndcg = dcg / (fred[0] + 1e-10f);
        atomicAdd(&ws[WS_ACC], ndcg);
        __threadfence();
        int old = atomicAdd((int*)ws + WS_GCTR, 1);
        if (old == B - 1)
            out[0] = -atomicAdd(&ws[WS_ACC], 0.0f) * (1.0f / (float)B);
    }
}

extern "C" void kernel_launch(void* const* d_in, const int* in_sizes, int n_in,
                              void* d_out, int out_size, void* d_ws, size_t ws_size,
                              hipStream_t stream) {
    const float* preds  = (const float*)d_in[0];
    const float* target = (const float*)d_in[1];
    float* out = (float*)d_out;
    float* ws  = (float*)d_ws;

    pair_kernel<<<B * 16, 256, 0, stream>>>(preds, target, ws);
    gf_kernel<<<B * 4, 256, 0, stream>>>(target, ws, out);
}

// Round 11
// 86.339 us; speedup vs baseline: 1.0574x; 1.0574x over previous
//
#include <hip/hip_runtime.h>
#include <hip/hip_fp16.h>

#define B 128
#define L 1024

#if __has_builtin(__builtin_amdgcn_exp2f)
#define EXP2(x) __builtin_amdgcn_exp2f(x)
#else
#define EXP2(x) __expf((x) * 0.6931471805599453f)
#endif

typedef unsigned int uint4v __attribute__((ext_vector_type(4)));
typedef float f32x2 __attribute__((ext_vector_type(2)));

// ws layout (floats):
//   [0..2048)  per-block dcg partials: idx = b*16 + iseg
//   [2048]     ndcg accumulator      (zeroed by pair_kernel block 0)
//   [2049]     completion counter    (zeroed by pair_kernel block 0)
#define WS_ACC  2048
#define WS_GCTR 2049

// erfc(|y|) ~= exp(-(1.12838 y + 0.6446 y^2 + 0.0745 y^3)), |dPhi| <= ~2.5e-4,
// y = diff/2 (prescaled into the f16 row). Constants pre-multiplied by
// -log2(e) so v_exp_f16 computes exp2 directly.
#define K1f -1.6279072f
#define K2f -0.9299637f
#define K3f -0.1074808f

// one packed evaluation: du holds 2 f16 j-values; acc += erf(y_i - y_j) x2.
// Measured-best session build (86.99 us, absmax 0.0): hexp2 intrinsics
// (gfx950 has no op_sel on VOP3 f16 VOP1 — R14 lesson), v_bfi sign transfer,
// packed-f32 window flush. Tri decomposition (R15-R18) measured net-negative:
// 0.53x erf work lost to ws round-trip + gather + atomic tail (+2..+8 us).
__device__ __forceinline__ void term2(unsigned int du, __half2 pi2,
                                      __half2 k1, __half2 k2, __half2 k3,
                                      __half2 one2, __half2& acc) {
    __half2 pj = __builtin_bit_cast(__half2, du);
    __half2 d  = __hsub2(pi2, pj);
    unsigned int dbits = __builtin_bit_cast(unsigned int, d);
    __half2 a  = __builtin_bit_cast(__half2, dbits & 0x7fff7fffu); // |d| both halves
    __half2 t  = __hfma2(k3, a, k2);
    __half2 u  = __hfma2(t,  a, k1);
    __half2 w  = __hmul2(a, u);                      // <= 0
    __half2 e  = __halves2half2(hexp2(__low2half(w)),
                                hexp2(__high2half(w)));   // ~= erfc(|y|)
    __half2 r  = __hsub2(one2, e);                   // >= 0, sign bits clear
    // canonical bfi pattern: (d & mask) | (r & ~mask) -> v_bfi_b32
    unsigned int rs = (dbits & 0x80008000u)
                    | (__builtin_bit_cast(unsigned int, r) & 0x7fff7fffu);
    acc = __hadd2(acc, __builtin_bit_cast(__half2, rs));  // erf(y), signed
}

__device__ __forceinline__ f32x2 h2f(__half2 h) {
    float2 f = __half22float2(h);
    f32x2 r; r.x = f.x; r.y = f.y;
    return r;
}

// grid = B*16 = 2048 blocks, 256 threads -> 8 blocks/CU -> 32 waves/CU (HW
// max). Block (b, iseg) owns 64 i's; thread (il = tid&63, jq = tid>>6)
// sums its 256-j quarter from the 2KB f16 LDS row with 8 independent half2
// accumulator chains (f32 flush every window; |acc|<=8 so f16 rounding is
// negligible). j-pointer is wave-uniform. NO global atomics/fences here
// (R6 lesson); one plain partial store per block.
__global__ __launch_bounds__(256, 8) void pair_kernel(const float* __restrict__ preds,
                                                      const float* __restrict__ target,
                                                      float* __restrict__ ws) {
    __shared__ __align__(16) __half sph[L];   // row * 0.5, f16
    __shared__ float red[256];                // cross-quarter E reduction

    const int blk  = blockIdx.x;
    const int b    = blk >> 4;
    const int iseg = blk & 15;
    const int tid  = threadIdx.x;
    const int il   = tid & 63;                // i_lane
    const int jq   = tid >> 6;                // j quarter (0..3) == wave id

    if (blk == 0 && tid == 0) {
        ws[WS_ACC] = 0.0f;                    // visible to finish_kernel at
        ((int*)ws)[WS_GCTR] = 0;              // dispatch boundary
    }

    const float* prow = preds + b * L;

    // stage row as f16, prescaled by 0.5 (erf argument is diff/2)
    float4 v4 = reinterpret_cast<const float4*>(prow)[tid];
    __half2 h01 = __floats2half2_rn(0.5f * v4.x, 0.5f * v4.y);
    __half2 h23 = __floats2half2_rn(0.5f * v4.z, 0.5f * v4.w);
    reinterpret_cast<__half2*>(sph)[tid * 2 + 0] = h01;
    reinterpret_cast<__half2*>(sph)[tid * 2 + 1] = h23;

    const int i = iseg * 64 + il;
    const float tgt = (tid < 64) ? target[b * L + iseg * 64 + tid] : 0.0f;

    __syncthreads();

    const __half2 pi2  = __half2half2(sph[i]);
    const __half2 k1   = __floats2half2_rn(K1f, K1f);
    const __half2 k2   = __floats2half2_rn(K2f, K2f);
    const __half2 k3   = __floats2half2_rn(K3f, K3f);
    const __half2 one2 = __floats2half2_rn(1.0f, 1.0f);
    const __half2 z2   = __floats2half2_rn(0.0f, 0.0f);

    // this wave's j-quarter: 256 f16 = 32 uint4 (each uint4 = 8 terms)
    const uint4v* basep = reinterpret_cast<const uint4v*>(sph + jq * 256);

    float E = 0.0f;
    for (int wdw = 0; wdw < 2; ++wdw) {       // 2 windows x 128 terms
        __half2 A0 = z2, A1 = z2, A2 = z2, A3 = z2,
                A4 = z2, A5 = z2, A6 = z2, A7 = z2;
        #pragma unroll
        for (int m = 0; m < 8; ++m) {         // 2 uint4 per step, 8 chains
            uint4v q0 = basep[wdw * 16 + m * 2 + 0];
            uint4v q1 = basep[wdw * 16 + m * 2 + 1];
            term2(q0.x, pi2, k1, k2, k3, one2, A0);
            term2(q0.y, pi2, k1, k2, k3, one2, A1);
            term2(q0.z, pi2, k1, k2, k3, one2, A2);
            term2(q0.w, pi2, k1, k2, k3, one2, A3);
            term2(q1.x, pi2, k1, k2, k3, one2, A4);
            term2(q1.y, pi2, k1, k2, k3, one2, A5);
            term2(q1.z, pi2, k1, k2, k3, one2, A6);
            term2(q1.w, pi2, k1, k2, k3, one2, A7);
        }
        // packed-f32 flush: v_pk_add_f32 tree (7 pk adds) vs 15 scalar adds
        f32x2 s01 = (h2f(A0) + h2f(A1)) + (h2f(A2) + h2f(A3));
        f32x2 s45 = (h2f(A4) + h2f(A5)) + (h2f(A6) + h2f(A7));
        f32x2 s   = s01 + s45;
        E += s.x + s.y;
    }

    // cross-quarter combine in LDS; wave 0 finishes the 64 i's
    red[tid] = E;
    __syncthreads();

    if (tid < 64) {
        float Es = (red[tid] + red[tid + 64]) + (red[tid + 128] + red[tid + 192]);
        // sum_j Phi = L/2 + Es/2 (diag term is exactly 0); er+1 = 513.5 + Es/2
        float er1 = 513.5f + 0.5f * Es;
        float g = EXP2(tgt) - 1.0f;           // 2^t - 1, exact for integer grades
        float contrib = g * __builtin_amdgcn_rcpf(__log2f(er1));
        #pragma unroll
        for (int off = 32; off > 0; off >>= 1)
            contrib += __shfl_down(contrib, off);
        if (tid == 0)
            ws[blk] = contrib;                // plain store, disjoint slot
    }
}

// grid = B blocks, 256 threads. Block b: combine 16 dcg partials, counting-sort
// IDCG (grades are ints 0..4), ndcg; last block writes the final scalar.
__global__ __launch_bounds__(256) void finish_kernel(const float* __restrict__ target,
                                                     float* __restrict__ ws,
                                                     float* __restrict__ out) {
    __shared__ unsigned long long cred[256];
    __shared__ float2 fred[256];

    const int b   = blockIdx.x;
    const int tid = threadIdx.x;
    const float* trow = target + b * L;

    // packed 16-bit counts of grades >=4,>=3,>=2,>=1 (max 1024 fits)
    unsigned long long cnt = 0ull;
    #pragma unroll
    for (int k = 0; k < 4; ++k) {
        float t = trow[tid + k * 256];
        cnt += ((unsigned long long)(t > 3.5f) << 48)
             + ((unsigned long long)(t > 2.5f) << 32)
             + ((unsigned long long)(t > 1.5f) << 16)
             + ((unsigned long long)(t > 0.5f));
    }
    cred[tid] = cnt;
    __syncthreads();
    #pragma unroll
    for (int s = 128; s > 0; s >>= 1) {
        if (tid < (unsigned)s) cred[tid] += cred[tid + s];
        __syncthreads();
    }
    unsigned long long tot = cred[0];
    const int n4 = (int)(tot >> 48) & 0xFFFF;
    const int n3 = (int)(tot >> 32) & 0xFFFF;
    const int n2 = (int)(tot >> 16) & 0xFFFF;
    const int n1 = (int)(tot)       & 0xFFFF;

    // parallel IDCG; joint reduction with the 16 dcg partials of this row
    float idcg_p = 0.0f;
    #pragma unroll
    for (int k = 0; k < 4; ++k) {
        int pos = tid + 1 + k * 256;
        float gain = (pos <= n4) ? 15.0f : (pos <= n3) ? 7.0f :
                     (pos <= n2) ? 3.0f  : (pos <= n1) ? 1.0f : 0.0f;
        idcg_p += gain * __builtin_amdgcn_rcpf(__log2f((float)pos + 1.0f));
    }
    float dcg_p = (tid < 16) ? ws[b * 16 + tid] : 0.0f;
    fred[tid] = make_float2(idcg_p, dcg_p);
    __syncthreads();
    #pragma unroll
    for (int s = 128; s > 0; s >>= 1) {
        if (tid < (unsigned)s) {
            float2 x = fred[tid], y = fred[tid + s];
            fred[tid] = make_float2(x.x + y.x, x.y + y.y);
        }
        __syncthreads();
    }

    if (tid == 0) {
        float ndcg = fred[0].y / (fred[0].x + 1e-10f);
        atomicAdd(&ws[WS_ACC], ndcg);
        __threadfence();
        int old = atomicAdd((int*)ws + WS_GCTR, 1);
        if (old == B - 1) {
            float acc = atomicAdd(&ws[WS_ACC], 0.0f);  // coherent read
            out[0] = -acc * (1.0f / (float)B);
        }
    }
}

extern "C" void kernel_launch(void* const* d_in, const int* in_sizes, int n_in,
                              void* d_out, int out_size, void* d_ws, size_t ws_size,
                              hipStream_t stream) {
    const float* preds  = (const float*)d_in[0];
    const float* target = (const float*)d_in[1];
    float* out = (float*)d_out;
    float* ws  = (float*)d_ws;

    pair_kernel<<<B * 16, 256, 0, stream>>>(preds, target, ws);
    finish_kernel<<<B, 256, 0, stream>>>(target, ws, out);
}